// Round 9
// baseline (210.630 us; speedup 1.0000x reference)
//
#include <hip/hip_runtime.h>

#define HH 256
#define WW 512
#define CC 64
#define CO 16
#define DD 48            // MAX_DISPARITY
#define ND (DD + 1)      // 49 disparity planes

typedef float f32x4 __attribute__((ext_vector_type(4)));

// Kernel 1: per-pixel 16x64 matvec; bias folded into L.
__global__ __launch_bounds__(256) void lr_project(
    const float* __restrict__ left, const float* __restrict__ right,
    const float* __restrict__ Wop, const float* __restrict__ bop,
    float* __restrict__ Lout, float* __restrict__ Rout)
{
    const int tid = blockIdx.x * blockDim.x + threadIdx.x;  // 0 .. H*W-1
    const int x = tid & (WW - 1);
    const int y = tid >> 9;   // /512

    float accL[CO], accR[CO];
#pragma unroll
    for (int o = 0; o < CO; ++o) { accL[o] = 0.0f; accR[o] = 0.0f; }

#pragma unroll 4
    for (int c = 0; c < CC; ++c) {
        const float l = left [(c * HH + y) * WW + x];
        const float r = right[(c * HH + y) * WW + x];
#pragma unroll
        for (int o = 0; o < CO; ++o) {
            accL[o] += Wop[o * (2 * CC) + c]      * l;
            accR[o] += Wop[o * (2 * CC) + CC + c] * r;
        }
    }

#pragma unroll
    for (int o = 0; o < CO; ++o) {
        Lout[(o * HH + y) * WW + x] = accL[o] + bop[o];   // bias folded
        Rout[(o * HH + y) * WW + x] = accR[o];
    }
}

// Kernel 2: fill-kernel clone. 1024 waves (4/CU); each wave owns a
// CONTIGUOUS 392 KB run of the output and walks it monotonically, 1 KB
// (dwordx4 x 64 lanes) per step. Because L's (o,y,x) layout matches the
// output's per-plane layout, the L and R read pointers ALSO advance
// linearly by 1 KB per step (L2-resident). Plain stores (through L2,
// no set-aliasing since the walk is contiguous). At most one (o,d)
// boundary per wave -> o,d,masks hoisted per segment.
__global__ __launch_bounds__(256) void assemble_stream(
    const float* __restrict__ L, const float* __restrict__ R,
    float* __restrict__ out)
{
    const int tid  = blockIdx.x * blockDim.x + threadIdx.x;
    const int wave = tid >> 6;          // 0..1023
    const int lane = tid & 63;

    int v = wave * 392;                 // 1KB-unit index; total 1024*392 = 401408
    const int vend = v + 392;

    float* op = out + (size_t)v * 256 + lane * 4;
    const ptrdiff_t RminusL = R - L;

    while (v < vend) {
        const int od = v >> 9;          // 0..783, wave-uniform
        const int o  = od / ND;
        const int d  = od - o * ND;
        const int segend = min(vend, (od + 1) << 9);
        int w = v & 511;                // position inside plane

        // masks apply only to even-w steps (x = lane*4 < 256); odd w has x>=256>d
        const int xb = lane * 4;
        const float m0 = (xb + 0 >= d) ? 1.0f : 0.0f;
        const float m1 = (xb + 1 >= d) ? 1.0f : 0.0f;
        const float m2 = (xb + 2 >= d) ? 1.0f : 0.0f;
        const float m3 = (xb + 3 >= d) ? 1.0f : 0.0f;

        const float* lp = L + (size_t)o * (HH * WW) + (size_t)w * 256 + lane * 4;
        const float* rp = lp + RminusL - d;   // may dip 48 floats into L region: valid, masked

#pragma unroll 4
        for (; v < segend; ++v, ++w) {
            f32x4 lv = *reinterpret_cast<const f32x4*>(lp);
            f32x4 rv;                          // 4B-aligned 16B load
            __builtin_memcpy(&rv, rp, sizeof(rv));

            f32x4 ov;
            if (w & 1) {                       // x >= 256: never masked
                ov.x = lv.x + rv.x;
                ov.y = lv.y + rv.y;
                ov.z = lv.z + rv.z;
                ov.w = lv.w + rv.w;
            } else {
                ov.x = lv.x + m0 * rv.x;
                ov.y = lv.y + m1 * rv.y;
                ov.z = lv.z + m2 * rv.z;
                ov.w = lv.w + m3 * rv.w;
            }
            *reinterpret_cast<f32x4*>(op) = ov;   // plain store (through L2)

            lp += 256; rp += 256; op += 256;
        }
    }
}

extern "C" void kernel_launch(void* const* d_in, const int* in_sizes, int n_in,
                              void* d_out, int out_size, void* d_ws, size_t ws_size,
                              hipStream_t stream) {
    const float* left  = (const float*)d_in[0];
    const float* right = (const float*)d_in[1];
    const float* Wop   = (const float*)d_in[2];
    const float* bop   = (const float*)d_in[3];
    float* out = (float*)d_out;

    float* Lws = (float*)d_ws;                      // CO*H*W floats = 8 MB (L + b)
    float* Rws = Lws + (size_t)CO * HH * WW;        // next 8 MB

    lr_project<<<(HH * WW) / 256, 256, 0, stream>>>(left, right, Wop, bop, Lws, Rws);

    // 256 blocks x 256 threads = 1024 waves, 4 per CU — fill-kernel-like
    assemble_stream<<<256, 256, 0, stream>>>(Lws, Rws, out);
}

// Round 10
// 117.987 us; speedup vs baseline: 1.7852x; 1.7852x over previous
//
#include <hip/hip_runtime.h>

#define HH 256
#define WW 512
#define CC 64
#define CO 16
#define DD 48            // MAX_DISPARITY
#define ND (DD + 1)      // 49 disparity planes
#define PLANE (HH * WW)  // 131072 floats per (o) plane
#define UNITS_PER_O (ND * 512)   // 25088 1KB-units per o
#define UNITS_PER_BLOCK 392
#define WAVE_UNITS 98

typedef float f32x4 __attribute__((ext_vector_type(4)));

// Kernel 1: per-pixel 16x64 matvec; bias folded into L.
__global__ __launch_bounds__(256) void lr_project(
    const float* __restrict__ left, const float* __restrict__ right,
    const float* __restrict__ Wop, const float* __restrict__ bop,
    float* __restrict__ Lout, float* __restrict__ Rout)
{
    const int tid = blockIdx.x * blockDim.x + threadIdx.x;  // 0 .. H*W-1
    const int x = tid & (WW - 1);
    const int y = tid >> 9;   // /512

    float accL[CO], accR[CO];
#pragma unroll
    for (int o = 0; o < CO; ++o) { accL[o] = 0.0f; accR[o] = 0.0f; }

#pragma unroll 4
    for (int c = 0; c < CC; ++c) {
        const float l = left [(c * HH + y) * WW + x];
        const float r = right[(c * HH + y) * WW + x];
#pragma unroll
        for (int o = 0; o < CO; ++o) {
            accL[o] += Wop[o * (2 * CC) + c]      * l;
            accR[o] += Wop[o * (2 * CC) + CC + c] * r;
        }
    }

#pragma unroll
    for (int o = 0; o < CO; ++o) {
        Lout[(o * HH + y) * WW + x] = accL[o] + bop[o];   // bias folded
        Rout[(o * HH + y) * WW + x] = accR[o];
    }
}

// Kernel 2: contiguous per-wave monotone walk + 16 waves/CU + XCD-local reads.
// 1024 blocks; block b -> XCD g=b%8 (round-robin HW mapping). XCD g owns
// o in {2g, 2g+1}: its L2 read set = 2 MB of L/R. Each of the block's 4
// waves walks 98 contiguous 1KB units; out/L/R pointers all advance 1 KB
// per step. NT stores keep the write stream from evicting the read set.
__global__ __launch_bounds__(256) void assemble_xcd(
    const float* __restrict__ L, const float* __restrict__ R,
    float* __restrict__ out)
{
    const int g    = blockIdx.x & 7;          // XCD slot
    const int k    = blockIdx.x >> 3;         // 0..127 within XCD
    const int wv   = threadIdx.x >> 6;        // 0..3
    const int lane = threadIdx.x & 63;

    int v = 2 * g * UNITS_PER_O + k * UNITS_PER_BLOCK + wv * WAVE_UNITS;
    const int vend = v + WAVE_UNITS;

    float* op = out + (size_t)v * 256 + lane * 4;
    const ptrdiff_t RminusL = R - L;
    const int xb = lane * 4;

    while (v < vend) {
        const int od = v >> 9;                // wave-uniform
        const int o  = od / ND;
        const int d  = od - o * ND;
        const int segend = min(vend, (od + 1) << 9);
        int w = v & 511;                      // unit within plane

        // masks used only on even-w units (x = xb < 256); odd units x>=256>d
        const float m0 = (xb + 0 >= d) ? 1.0f : 0.0f;
        const float m1 = (xb + 1 >= d) ? 1.0f : 0.0f;
        const float m2 = (xb + 2 >= d) ? 1.0f : 0.0f;
        const float m3 = (xb + 3 >= d) ? 1.0f : 0.0f;

        const float* lp = L + (size_t)o * PLANE + (size_t)w * 256 + xb;
        const float* rp = lp + RminusL - d;   // may dip <=48 floats into L region: valid, masked

#pragma unroll 4
        for (; v < segend; ++v, ++w) {
            f32x4 lv = *reinterpret_cast<const f32x4*>(lp);
            f32x4 rv;                         // 4B-aligned 16B load
            __builtin_memcpy(&rv, rp, sizeof(rv));

            f32x4 ov;
            if (w & 1) {                      // x >= 256: never masked
                ov.x = lv.x + rv.x;
                ov.y = lv.y + rv.y;
                ov.z = lv.z + rv.z;
                ov.w = lv.w + rv.w;
            } else {
                ov.x = lv.x + m0 * rv.x;
                ov.y = lv.y + m1 * rv.y;
                ov.z = lv.z + m2 * rv.z;
                ov.w = lv.w + m3 * rv.w;
            }
            __builtin_nontemporal_store(ov, reinterpret_cast<f32x4*>(op));

            lp += 256; rp += 256; op += 256;
        }
    }
}

extern "C" void kernel_launch(void* const* d_in, const int* in_sizes, int n_in,
                              void* d_out, int out_size, void* d_ws, size_t ws_size,
                              hipStream_t stream) {
    const float* left  = (const float*)d_in[0];
    const float* right = (const float*)d_in[1];
    const float* Wop   = (const float*)d_in[2];
    const float* bop   = (const float*)d_in[3];
    float* out = (float*)d_out;

    float* Lws = (float*)d_ws;                      // CO*H*W floats = 8 MB (L + b)
    float* Rws = Lws + (size_t)CO * HH * WW;        // next 8 MB

    lr_project<<<(HH * WW) / 256, 256, 0, stream>>>(left, right, Wop, bop, Lws, Rws);

    // 1024 blocks x 256 threads = 4096 waves = 16 waves/CU
    assemble_xcd<<<1024, 256, 0, stream>>>(Lws, Rws, out);
}

// Round 11
// 113.125 us; speedup vs baseline: 1.8619x; 1.0430x over previous
//
#include <hip/hip_runtime.h>

#define HH 256
#define WW 512
#define CC 64
#define CO 16
#define DD 48            // MAX_DISPARITY; output has ND = 49 disparity planes
#define ND (DD + 1)
#define YQ 8             // y-chunks per plane
#define ROWS (HH / YQ)   // 32 rows per block

typedef float f32x4 __attribute__((ext_vector_type(4)));

// Kernel 1: per-pixel 16x64 matvec for both L and R projections (bias folded into L).
__global__ __launch_bounds__(256) void lr_project(
    const float* __restrict__ left, const float* __restrict__ right,
    const float* __restrict__ Wop, const float* __restrict__ bop,
    float* __restrict__ Lout, float* __restrict__ Rout)
{
    const int tid = blockIdx.x * blockDim.x + threadIdx.x;  // 0 .. H*W-1
    const int x = tid & (WW - 1);
    const int y = tid >> 9;   // /512

    float accL[CO], accR[CO];
#pragma unroll
    for (int o = 0; o < CO; ++o) { accL[o] = 0.0f; accR[o] = 0.0f; }

#pragma unroll 4
    for (int c = 0; c < CC; ++c) {
        const float l = left [(c * HH + y) * WW + x];
        const float r = right[(c * HH + y) * WW + x];
#pragma unroll
        for (int o = 0; o < CO; ++o) {
            accL[o] += Wop[o * (2 * CC) + c]      * l;
            accR[o] += Wop[o * (2 * CC) + CC + c] * r;
        }
    }

#pragma unroll
    for (int o = 0; o < CO; ++o) {
        Lout[(o * HH + y) * WW + x] = accL[o] + bop[o];   // bias folded
        Rout[(o * HH + y) * WW + x] = accR[o];
    }
}

// Kernel 2: R5 structure (contiguous 64 KB slab per block, monotone 4 KB/iter
// advance, XCD-clustered o) with PLAIN stores — A/B: does a contiguous plain
// store stream write-combine in L2 and reach fill-kernel BW (6.85 TB/s)?
__global__ __launch_bounds__(256) void assemble(
    const float* __restrict__ L, const float* __restrict__ R,
    float* __restrict__ out)
{
    // blockIdx.x = g + 8*(oh*392 + d*8 + yq), g = XCD slot
    const int g  = blockIdx.x & 7;
    const int j  = blockIdx.x >> 3;          // 0..783
    const int oh = j / 392;                  // 0..1
    const int r  = j - 392 * oh;
    const int d  = r >> 3;                   // 0..48
    const int yq = r & 7;                    // 0..7
    const int o  = g + 8 * oh;               // 0..15

    const int t   = threadIdx.x;
    const int x   = (t & 127) << 2;          // 0..508, step 4
    const int yr0 = t >> 7;                  // 0 or 1
    const int y0  = yq * ROWS + yr0;

    // per-thread constant boundary masks (x, d fixed)
    const float m0 = (x + 0 >= d) ? 1.0f : 0.0f;
    const float m1 = (x + 1 >= d) ? 1.0f : 0.0f;
    const float m2 = (x + 2 >= d) ? 1.0f : 0.0f;
    const float m3 = (x + 3 >= d) ? 1.0f : 0.0f;

    const float* Lp = &L[(o * HH + y0) * WW + x];
    const float* Rp = Lp + (R - L) - d;      // R row, shifted (dips into L region: valid, masked)
    float*       op = &out[((size_t)(o * ND + d) * HH + y0) * WW + x];

#pragma unroll
    for (int k = 0; k < ROWS / 2; ++k) {     // 16 iters, 2-row (4 KB) stride
        const f32x4 lv = *reinterpret_cast<const f32x4*>(Lp);   // L + b (aligned)
        f32x4 rv;                             // 4B-aligned 16B load
        __builtin_memcpy(&rv, Rp, sizeof(rv));

        f32x4 ov;
        ov.x = lv.x + m0 * rv.x;
        ov.y = lv.y + m1 * rv.y;
        ov.z = lv.z + m2 * rv.z;
        ov.w = lv.w + m3 * rv.w;
        *reinterpret_cast<f32x4*>(op) = ov;   // PLAIN store (through L2)

        Lp += 2 * WW;
        Rp += 2 * WW;
        op += 2 * WW;
    }
}

extern "C" void kernel_launch(void* const* d_in, const int* in_sizes, int n_in,
                              void* d_out, int out_size, void* d_ws, size_t ws_size,
                              hipStream_t stream) {
    const float* left  = (const float*)d_in[0];
    const float* right = (const float*)d_in[1];
    const float* Wop   = (const float*)d_in[2];
    const float* bop   = (const float*)d_in[3];
    float* out = (float*)d_out;

    float* Lws = (float*)d_ws;                      // CO*H*W floats = 8 MB (L + b)
    float* Rws = Lws + (size_t)CO * HH * WW;        // next 8 MB

    lr_project<<<(HH * WW) / 256, 256, 0, stream>>>(left, right, Wop, bop, Lws, Rws);

    // 16 o * 49 d * 8 yq = 6272 blocks, one 64 KB slab each
    assemble<<<CO * ND * YQ, 256, 0, stream>>>(Lws, Rws, out);
}

// Round 12
// 104.602 us; speedup vs baseline: 2.0136x; 1.0815x over previous
//
#include <hip/hip_runtime.h>

#define HH 256
#define WW 512
#define CC 64
#define CO 16
#define DD 48   // MAX_DISPARITY; output has D+1 = 49 disparity planes

typedef float f32x4 __attribute__((ext_vector_type(4)));

// Kernel 1: per-pixel 16x64 matvec for both L and R projections.
__global__ __launch_bounds__(256) void lr_project(
    const float* __restrict__ left, const float* __restrict__ right,
    const float* __restrict__ Wop,
    float* __restrict__ Lout, float* __restrict__ Rout)
{
    const int tid = blockIdx.x * blockDim.x + threadIdx.x;  // 0 .. H*W-1
    const int x = tid & (WW - 1);
    const int y = tid >> 9;   // /512

    float accL[CO], accR[CO];
#pragma unroll
    for (int o = 0; o < CO; ++o) { accL[o] = 0.0f; accR[o] = 0.0f; }

#pragma unroll 4
    for (int c = 0; c < CC; ++c) {
        const float l = left [(c * HH + y) * WW + x];
        const float r = right[(c * HH + y) * WW + x];
#pragma unroll
        for (int o = 0; o < CO; ++o) {
            accL[o] += Wop[o * (2 * CC) + c]      * l;
            accR[o] += Wop[o * (2 * CC) + CC + c] * r;
        }
    }

#pragma unroll
    for (int o = 0; o < CO; ++o) {
        Lout[(o * HH + y) * WW + x] = accL[o];
        Rout[(o * HH + y) * WW + x] = accR[o];
    }
}

// Kernel 2: out[o,d,y,x] = L[o,y,x] + (x>=d ? R[o,y,x-d] : 0) + b[o]
// One thread per (o,y,x4). Preload the entire R window R[x-48 .. x+3]
// (13 aligned float4 -> 52 registers, each vector fully valid or fully OOB),
// then 49 iterations of pure {4 adds + 1 NT dwordx4 store} — no in-loop loads,
// no serial dependence. Store pointer walks the disparity-plane stride.
__global__ __launch_bounds__(256) void assemble(
    const float* __restrict__ L, const float* __restrict__ R,
    const float* __restrict__ bop, float* __restrict__ out)
{
    const int tid = blockIdx.x * blockDim.x + threadIdx.x;  // 0 .. CO*H*W/4-1
    const int x4 = tid & 127;        // W/4 = 128
    const int t  = tid >> 7;
    const int y  = t & 255;          // H = 256
    const int o  = t >> 8;

    const int x   = x4 * 4;
    const int row = (o * HH + y) * WW;

    const float  b  = bop[o];
    const f32x4  lv = *reinterpret_cast<const f32x4*>(&L[row + x]);
    const float lb0 = lv.x + b, lb1 = lv.y + b, lb2 = lv.z + b, lb3 = lv.w + b;

    const float* Rrow = &R[row];

    // w[k] = R[row + x - 48 + k] for k=0..51 (zero where x-48+k < 0).
    float w[52];
#pragma unroll
    for (int jr = 0; jr < 13; ++jr) {
        const int j = 12 - jr;
        const int base = x - 48 + 4 * j;
        // speculative aligned load; base >= -48 stays inside d_ws (L region)
        f32x4 v = *reinterpret_cast<const f32x4*>(&Rrow[base]);
        const bool ok = (base >= 0);
        w[4 * j + 0] = ok ? v.x : 0.0f;
        w[4 * j + 1] = ok ? v.y : 0.0f;
        w[4 * j + 2] = ok ? v.z : 0.0f;
        w[4 * j + 3] = ok ? v.w : 0.0f;
    }

    float* outp = &out[((size_t)(o * (DD + 1)) * HH + y) * WW + x];

#pragma unroll
    for (int d = 0; d <= DD; ++d) {
        f32x4 ov;
        ov.x = lb0 + w[48 - d];
        ov.y = lb1 + w[49 - d];
        ov.z = lb2 + w[50 - d];
        ov.w = lb3 + w[51 - d];
        __builtin_nontemporal_store(ov, reinterpret_cast<f32x4*>(outp));
        outp += HH * WW;             // next disparity plane
    }
}

extern "C" void kernel_launch(void* const* d_in, const int* in_sizes, int n_in,
                              void* d_out, int out_size, void* d_ws, size_t ws_size,
                              hipStream_t stream) {
    const float* left  = (const float*)d_in[0];
    const float* right = (const float*)d_in[1];
    const float* Wop   = (const float*)d_in[2];
    const float* bop   = (const float*)d_in[3];
    float* out = (float*)d_out;

    float* Lws = (float*)d_ws;                      // CO*H*W floats = 8 MB
    float* Rws = Lws + (size_t)CO * HH * WW;        // next 8 MB

    lr_project<<<(HH * WW) / 256, 256, 0, stream>>>(left, right, Wop, Lws, Rws);
    assemble<<<(CO * HH * (WW / 4)) / 256, 256, 0, stream>>>(Lws, Rws, bop, out);
}